// Round 5
// baseline (239.681 us; speedup 1.0000x reference)
//
#include <hip/hip_runtime.h>
#include <cstdint>

#define D_MODEL 2048
#define NKV 8
#define GQ 4
#define DK 64
#define B_ 2
#define S_ 2048
#define MS (B_*S_)     // 4096
#define KVD (NKV*DK)   // 512

typedef unsigned short u16;
typedef __attribute__((ext_vector_type(8))) short bf16x8;
typedef __attribute__((ext_vector_type(4))) short bf16x4;
typedef __attribute__((ext_vector_type(4))) float f32x4;
typedef __attribute__((ext_vector_type(16))) float f32x16;
typedef __attribute__((ext_vector_type(4))) unsigned short u16x4;

__device__ __forceinline__ u16 f2bf(float f) {
    union { float f; uint32_t u; } x; x.f = f;
    uint32_t u = x.u;
    uint32_t r = (u + 0x7FFFu + ((u >> 16) & 1u)) >> 16;
    return (u16)r;
}
__device__ __forceinline__ float bf2f(u16 h) {
    union { uint32_t u; float f; } x; x.u = ((uint32_t)h) << 16;
    return x.f;
}

__device__ __forceinline__ void gload_lds16(const void* g, void* lds) {
    __builtin_amdgcn_global_load_lds(
        (const __attribute__((address_space(1))) void*)g,
        (__attribute__((address_space(3))) void*)lds, 16, 0, 0);
}

__device__ __forceinline__ bf16x8 cvt8(float4 a, float4 b) {
    union { unsigned u[4]; bf16x8 v; } r;
    asm("v_cvt_pk_bf16_f32 %0, %1, %2" : "=v"(r.u[0]) : "v"(a.x), "v"(a.y));
    asm("v_cvt_pk_bf16_f32 %0, %1, %2" : "=v"(r.u[1]) : "v"(a.z), "v"(a.w));
    asm("v_cvt_pk_bf16_f32 %0, %1, %2" : "=v"(r.u[2]) : "v"(b.x), "v"(b.y));
    asm("v_cvt_pk_bf16_f32 %0, %1, %2" : "=v"(r.u[3]) : "v"(b.z), "v"(b.w));
    return r.v;
}

// =================== merged Q/K/V projection GEMM ===================
// 256x128 tile, BK=64, 512 thr (8 waves: 4M x 2N, per-wave 64x64).
// A,B read as fp32, converted in-register, ds_write with 3-bit XOR swizzle.
// Blocks 0..255: Q-proj; 256..319: K-proj; 320..383: V-proj (transposed out).
__global__ __launch_bounds__(512, 2)
void gemm_qkv(const float* __restrict__ Aq, const float* __restrict__ Ak,
              const float* __restrict__ Av,
              const float* __restrict__ Wq, const float* __restrict__ Wk,
              const float* __restrict__ Wv,
              const float* __restrict__ bq, const float* __restrict__ bk,
              const float* __restrict__ bv,
              u16* __restrict__ Qp, u16* __restrict__ Kp, u16* __restrict__ Vt) {
    __shared__ __align__(16) u16 SA[2][256 * 64];
    __shared__ __align__(16) u16 SB[2][128 * 64];
    const int tid = threadIdx.x;
    const int lane = tid & 63;
    const int fr = lane & 15, fq = lane >> 4;
    const int wid = tid >> 6;
    const int wr = wid >> 1, wc = wid & 1;
    const int K = D_MODEL, NT = K / 64;

    const int bid = blockIdx.x;
    const int sw = (bid & 7) * 48 + (bid >> 3);      // bijective XCD swizzle (384)
    const float* A; const float* Bw; const float* bias;
    int seg, by, bx;
    if (sw < 256)      { seg = 0; A = Aq; Bw = Wq; bias = bq; by = sw >> 4;        bx = sw & 15; }
    else if (sw < 320) { seg = 1; A = Ak; Bw = Wk; bias = bk; by = (sw - 256) >> 2; bx = (sw - 256) & 3; }
    else               { seg = 2; A = Av; Bw = Wv; bias = bv; by = (sw - 320) >> 2; bx = (sw - 320) & 3; }
    const int m0 = by * 256, n0 = bx * 128;

    float4 ra[4][2], rb[2][2];
    auto LOADA = [&](int t) {
        const int k0 = t << 6;
#pragma unroll
        for (int j = 0; j < 4; ++j) {
            int idx = tid + j * 512, row = idx >> 3, c = idx & 7;
            const float* p = A + (size_t)(m0 + row) * K + k0 + c * 8;
            ra[j][0] = *(const float4*)p;
            ra[j][1] = *(const float4*)(p + 4);
        }
    };
    auto LOADB = [&](int t) {
        const int k0 = t << 6;
#pragma unroll
        for (int j = 0; j < 2; ++j) {
            int idx = tid + j * 512, row = idx >> 3, c = idx & 7;
            const float* p = Bw + (size_t)(n0 + row) * K + k0 + c * 8;
            rb[j][0] = *(const float4*)p;
            rb[j][1] = *(const float4*)(p + 4);
        }
    };
    auto WRITE = [&](int q) {
#pragma unroll
        for (int j = 0; j < 4; ++j) {
            int idx = tid + j * 512, row = idx >> 3, c = idx & 7;
            *(bf16x8*)((char*)&SA[q][0] + row * 128 + ((c ^ (row & 7)) * 16)) = cvt8(ra[j][0], ra[j][1]);
        }
#pragma unroll
        for (int j = 0; j < 2; ++j) {
            int idx = tid + j * 512, row = idx >> 3, c = idx & 7;
            *(bf16x8*)((char*)&SB[q][0] + row * 128 + ((c ^ (row & 7)) * 16)) = cvt8(rb[j][0], rb[j][1]);
        }
    };

    f32x4 acc[4][4] = {};
    const int arow = wr * 64, brow = wc * 64;

    LOADA(0); LOADB(0);
    WRITE(0);
    LOADA(1); LOADB(1);
    asm volatile("s_waitcnt lgkmcnt(0)" ::: "memory");
    __builtin_amdgcn_s_barrier();

    for (int t = 0; t < NT; ++t) {
        const int q = t & 1;
        const char* sa = (const char*)&SA[q][0];
        const char* sb = (const char*)&SB[q][0];
#pragma unroll
        for (int kk = 0; kk < 2; ++kk) {
            const int cs = (((kk << 2) | fq) ^ (fr & 7)) * 16;
            bf16x8 af[4], bfr[4];
#pragma unroll
            for (int m = 0; m < 4; ++m)
                af[m] = *(const bf16x8*)(sa + (size_t)(arow + m * 16 + fr) * 128 + cs);
#pragma unroll
            for (int n = 0; n < 4; ++n)
                bfr[n] = *(const bf16x8*)(sb + (size_t)(brow + n * 16 + fr) * 128 + cs);
            __builtin_amdgcn_s_setprio(1);
#pragma unroll
            for (int m = 0; m < 4; ++m)
#pragma unroll
                for (int n = 0; n < 4; ++n)
                    acc[m][n] = __builtin_amdgcn_mfma_f32_16x16x32_bf16(af[m], bfr[n], acc[m][n], 0, 0, 0);
            __builtin_amdgcn_s_setprio(0);
        }
        asm volatile("s_barrier" ::: "memory");          // reads of buf q done
        if (t + 1 < NT) {
            WRITE(q ^ 1);                                // stages tile t+1 (regs loaded earlier)
            if (t + 2 < NT) { LOADA(t + 2); LOADB(t + 2); }
            asm volatile("s_waitcnt lgkmcnt(0)" ::: "memory");
            __builtin_amdgcn_s_barrier();                // tile t+1 visible
        }
    }

    float bvv[4];
#pragma unroll
    for (int n = 0; n < 4; ++n) bvv[n] = bias[n0 + brow + n * 16 + fr];
#pragma unroll
    for (int m = 0; m < 4; ++m) {
        int grow0 = m0 + wr * 64 + m * 16 + fq * 4;
#pragma unroll
        for (int n = 0; n < 4; ++n) {
            int gcol = n0 + brow + n * 16 + fr;
#pragma unroll
            for (int r = 0; r < 4; ++r) {
                float v = acc[m][n][r] + bvv[n];
                int grow = grow0 + r;
                if (seg == 0)      Qp[(size_t)grow * D_MODEL + gcol] = f2bf(v);
                else if (seg == 1) Kp[(size_t)grow * KVD + gcol] = f2bf(v);
                else {
                    int b = grow >> 11, s = grow & (S_ - 1);
                    Vt[((size_t)b * KVD + gcol) * S_ + s] = f2bf(v);
                }
            }
        }
    }
}

// =================== O projection: A bf16 (gload_lds), B fp32 (reg-staged) ===================
__global__ __launch_bounds__(512, 2)
void gemm_o(const u16* __restrict__ A, const float* __restrict__ Bw,
            const float* __restrict__ bias, float* __restrict__ Cout) {
    __shared__ __align__(16) u16 SA[2][256 * 64];
    __shared__ __align__(16) u16 SB[2][128 * 64];
    const int tid = threadIdx.x;
    const int lane = tid & 63;
    const int fr = lane & 15, fq = lane >> 4;
    const int wid = tid >> 6;
    const int wr = wid >> 1, wc = wid & 1;
    const int K = D_MODEL, N = D_MODEL, NT = K / 64;

    const int bid = blockIdx.x;
    const int sw = (bid & 7) * 32 + (bid >> 3);
    const int by = sw >> 4, bx = sw & 15;
    const int m0 = by * 256, n0 = bx * 128;

    // A staging: pre-swizzled global source, linear LDS dest (content at slot c = chunk c^(row&7))
    auto GLOADA = [&](int t, int q) {
        const int k0 = t << 6;
#pragma unroll
        for (int j = 0; j < 4; ++j) {
            int idx = tid + j * 512, row = idx >> 3, c = idx & 7;
            gload_lds16(A + (size_t)(m0 + row) * K + k0 + ((c ^ (row & 7)) * 8),
                        &SA[q][(j * 512 + (tid >> 6) * 64) * 8]);
        }
    };
    float4 rb[2][2];
    auto LOADB = [&](int t) {
        const int k0 = t << 6;
#pragma unroll
        for (int j = 0; j < 2; ++j) {
            int idx = tid + j * 512, row = idx >> 3, c = idx & 7;
            const float* p = Bw + (size_t)(n0 + row) * K + k0 + c * 8;
            rb[j][0] = *(const float4*)p;
            rb[j][1] = *(const float4*)(p + 4);
        }
    };
    auto WRITEB = [&](int q) {
#pragma unroll
        for (int j = 0; j < 2; ++j) {
            int idx = tid + j * 512, row = idx >> 3, c = idx & 7;
            *(bf16x8*)((char*)&SB[q][0] + row * 128 + ((c ^ (row & 7)) * 16)) = cvt8(rb[j][0], rb[j][1]);
        }
    };

    f32x4 acc[4][4] = {};
    const int arow = wr * 64, brow = wc * 64;

    GLOADA(0, 0);
    asm volatile("" ::: "memory");
    LOADB(0);
    WRITEB(0);                                   // B-reg data-dep drains vmcnt past A(0)
    GLOADA(1, 1);
    asm volatile("" ::: "memory");
    LOADB(1);
    asm volatile("s_waitcnt lgkmcnt(0)" ::: "memory");
    __builtin_amdgcn_s_barrier();

    for (int t = 0; t < NT; ++t) {
        const int q = t & 1;
        const char* sa = (const char*)&SA[q][0];
        const char* sb = (const char*)&SB[q][0];
#pragma unroll
        for (int kk = 0; kk < 2; ++kk) {
            const int cs = (((kk << 2) | fq) ^ (fr & 7)) * 16;
            bf16x8 af[4], bfr[4];
#pragma unroll
            for (int m = 0; m < 4; ++m)
                af[m] = *(const bf16x8*)(sa + (size_t)(arow + m * 16 + fr) * 128 + cs);
#pragma unroll
            for (int n = 0; n < 4; ++n)
                bfr[n] = *(const bf16x8*)(sb + (size_t)(brow + n * 16 + fr) * 128 + cs);
            __builtin_amdgcn_s_setprio(1);
#pragma unroll
            for (int m = 0; m < 4; ++m)
#pragma unroll
                for (int n = 0; n < 4; ++n)
                    acc[m][n] = __builtin_amdgcn_mfma_f32_16x16x32_bf16(af[m], bfr[n], acc[m][n], 0, 0, 0);
            __builtin_amdgcn_s_setprio(0);
        }
        asm volatile("s_barrier" ::: "memory");
        if (t + 1 < NT) {
            asm volatile("s_waitcnt vmcnt(4)" ::: "memory");   // A(t+1) gloads landed (B(t+1) may fly)
            WRITEB(q ^ 1);
            if (t + 2 < NT) {
                GLOADA(t + 2, q);
                asm volatile("" ::: "memory");
                LOADB(t + 2);
            }
            asm volatile("s_waitcnt lgkmcnt(0)" ::: "memory");
            __builtin_amdgcn_s_barrier();
        }
    }

    float bvv[4];
#pragma unroll
    for (int n = 0; n < 4; ++n) bvv[n] = bias[n0 + brow + n * 16 + fr];
#pragma unroll
    for (int m = 0; m < 4; ++m) {
        int grow0 = m0 + wr * 64 + m * 16 + fq * 4;
#pragma unroll
        for (int n = 0; n < 4; ++n) {
            int gcol = n0 + brow + n * 16 + fr;
#pragma unroll
            for (int r = 0; r < 4; ++r)
                Cout[(size_t)(grow0 + r) * N + gcol] = acc[m][n][r] + bvv[n];
        }
    }
}

// ---------------- Flash attention (causal, GQA), LDS-staged K/V ----------------
__global__ __launch_bounds__(256, 4)
void attn_fwd(const u16* __restrict__ Qp, const u16* __restrict__ Kp,
              const u16* __restrict__ Vt, u16* __restrict__ AO) {
    __shared__ __align__(16) u16 Klds[2][4096];
    __shared__ __align__(16) u16 Vlds[2][4096];
    const int bid = blockIdx.x;
    const int qblk = 15 - (bid >> 6);
    const int rest = bid & 63;
    const int b = rest >> 5;
    const int kv = (rest >> 2) & 7;
    const int g = rest & 3;
    const int tid = threadIdx.x, w = tid >> 6, l = tid & 63;
    const int q31 = l & 31, hi = l >> 5;
    const int h = kv * GQ + g;
    const int qw = qblk * 128 + w * 32;
    const int q0 = qw + q31;

    const u16* kbase = Kp + (size_t)(b * S_) * KVD + kv * DK;
    const u16* vbase = Vt + ((size_t)b * KVD + kv * DK) * S_;

    const float SCALE = 0.125f * 1.44269504f;
    bf16x8 qf[4];
    const u16* qp = Qp + ((size_t)(b * S_) + q0) * D_MODEL + h * DK;
#pragma unroll
    for (int ks = 0; ks < 4; ++ks) {
        bf16x8 t = *(const bf16x8*)(qp + ks * 16 + hi * 8);
#pragma unroll
        for (int j = 0; j < 8; ++j) t[j] = (short)f2bf(bf2f((u16)t[j]) * SCALE);
        qf[ks] = t;
    }

    const int nt = 2 * qblk + 2;
    const int bound = (qw + 31) >> 6;

    auto STAGE = [&](int t, int bufsel) {
#pragma unroll
        for (int r = 0; r < 2; ++r) {
            int idx = r * 256 + tid;
            int row = idx >> 3;
            int slotK = (idx & 7) ^ (row & 7);
            int jV = (idx & 7) ^ ((row >> 1) & 7);
            u16* kdst = &Klds[bufsel][(r * 256 + w * 64) * 8];
            u16* vdst = &Vlds[bufsel][(r * 256 + w * 64) * 8];
            gload_lds16(kbase + (size_t)(t * 64 + row) * KVD + slotK * 8, kdst);
            gload_lds16(vbase + (size_t)row * S_ + t * 64 + jV * 8, vdst);
        }
    };

    f32x16 o0 = {}, o1 = {};
    float m_run = -1e30f, l_run = 0.f;

    STAGE(0, 0);
    __syncthreads();
    int cur = 0;
    for (int t = 0; t < nt; ++t) {
        if (t + 1 < nt) STAGE(t + 1, cur ^ 1);
        if (t <= bound) {
            const u16* Kc = Klds[cur];
            const u16* Vc = Vlds[cur];
            const int base0 = t * 64, base1 = t * 64 + 32;
            const bool act1 = (base1 <= qw + 31);

            f32x16 s0 = {};
            {
                const int row = q31;
#pragma unroll
                for (int ks = 0; ks < 4; ++ks) {
                    bf16x8 kf = *(const bf16x8*)&Kc[row * 64 + ((((ks << 1) | hi)) ^ (row & 7)) * 8];
                    s0 = __builtin_amdgcn_mfma_f32_32x32x16_bf16(kf, qf[ks], s0, 0, 0, 0);
                }
            }
            f32x16 s1 = {};
            if (act1) {
                const int row = 32 + q31;
#pragma unroll
                for (int ks = 0; ks < 4; ++ks) {
                    bf16x8 kf = *(const bf16x8*)&Kc[row * 64 + ((((ks << 1) | hi)) ^ (row & 7)) * 8];
                    s1 = __builtin_amdgcn_mfma_f32_32x32x16_bf16(kf, qf[ks], s1, 0, 0, 0);
                }
            }
            if (base0 + 31 > qw) {
#pragma unroll
                for (int r = 0; r < 16; ++r) {
                    int koff = (r & 3) + 8 * (r >> 2) + 4 * hi;
                    s0[r] = (base0 + koff <= q0) ? s0[r] : -1e30f;
                }
            }
            if (act1 && (base1 + 31 > qw)) {
#pragma unroll
                for (int r = 0; r < 16; ++r) {
                    int koff = (r & 3) + 8 * (r >> 2) + 4 * hi;
                    s1[r] = (base1 + koff <= q0) ? s1[r] : -1e30f;
                }
            }
            float pm = s0[0];
#pragma unroll
            for (int r = 1; r < 16; ++r) pm = fmaxf(pm, s0[r]);
            if (act1) {
#pragma unroll
                for (int r = 0; r < 16; ++r) pm = fmaxf(pm, s1[r]);
            }
            pm = fmaxf(pm, __shfl_xor(pm, 32));
            if (__any(pm > m_run + 8.0f)) {
                float mn = fmaxf(m_run, pm);
                float sc = __builtin_amdgcn_exp2f(m_run - mn);
                m_run = mn; l_run *= sc;
#pragma unroll
                for (int r = 0; r < 16; ++r) { o0[r] *= sc; o1[r] *= sc; }
            }
            float psum = 0.f;
#pragma unroll
            for (int r = 0; r < 16; ++r) { float p = __builtin_amdgcn_exp2f(s0[r] - m_run); s0[r] = p; psum += p; }
            if (act1) {
#pragma unroll
                for (int r = 0; r < 16; ++r) { float p = __builtin_amdgcn_exp2f(s1[r] - m_run); s1[r] = p; psum += p; }
            }
            l_run += psum;
            unsigned W0[8], W1[8];
#pragma unroll
            for (int tt = 0; tt < 8; ++tt)
                asm("v_cvt_pk_bf16_f32 %0, %1, %2" : "=v"(W0[tt]) : "v"(s0[2 * tt]), "v"(s0[2 * tt + 1]));
            if (act1) {
#pragma unroll
                for (int tt = 0; tt < 8; ++tt)
                    asm("v_cvt_pk_bf16_f32 %0, %1, %2" : "=v"(W1[tt]) : "v"(s1[2 * tt]), "v"(s1[2 * tt + 1]));
            }
#pragma unroll
            for (int sl = 0; sl < 2; ++sl) {
                union { unsigned u[4]; bf16x8 v; } bw;
#pragma unroll
                for (int i = 0; i < 4; ++i) bw.u[i] = W0[sl * 4 + i];
#pragma unroll
                for (int half = 0; half < 2; ++half) {
                    const int row = half * 32 + q31;
                    union { bf16x4 h4[2]; bf16x8 v; } vf;
                    int sa = (sl * 4 + hi) ^ (row & 14);
                    int sb = (sl * 4 + 2 + hi) ^ (row & 14);
                    vf.h4[0] = *(const bf16x4*)&Vc[row * 64 + sa * 4];
                    vf.h4[1] = *(const bf16x4*)&Vc[row * 64 + sb * 4];
                    if (half == 0) o0 = __builtin_amdgcn_mfma_f32_32x32x16_bf16(vf.v, bw.v, o0, 0, 0, 0);
                    else           o1 = __builtin_amdgcn_mfma_f32_32x32x16_bf16(vf.v, bw.v, o1, 0, 0, 0);
                }
            }
            if (act1) {
#pragma unroll
                for (int sl = 2; sl < 4; ++sl) {
                    union { unsigned u[4]; bf16x8 v; } bw;
#pragma unroll
                    for (int i = 0; i < 4; ++i) bw.u[i] = W1[(sl - 2) * 4 + i];
#pragma unroll
                    for (int half = 0; half < 2; ++half) {
                        const int row = half * 32 + q31;
                        union { bf16x4 h4[2]; bf16x8 v; } vf;
                        int sa = (sl * 4 + hi) ^ (row & 14);
                        int sb = (sl * 4 + 2 + hi) ^ (row & 14);
                        vf.h4[0] = *(const bf16x4*)&Vc[row * 64 + sa * 4];
                        vf.h4[1] = *(const bf16x4*)&Vc[row * 64 + sb * 4];
                        if (half == 0) o0 = __builtin_amdgcn_mfma_f32_32x32x16_bf16(vf.v, bw.v, o0, 0, 0, 0);
                        else           o1 = __builtin_amdgcn_mfma_f32_32x32x16_bf16(vf.v, bw.v, o1, 0, 0, 0);
                    }
                }
            }
        }
        __syncthreads();
        cur ^= 1;
    }

    float lt = l_run + __shfl_xor(l_run, 32);
    float rl = 1.0f / lt;
    u16* op = AO + ((size_t)(b * S_) + q0) * D_MODEL + h * DK;
#pragma unroll
    for (int half = 0; half < 2; ++half) {
#pragma unroll
        for (int rr = 0; rr < 16; rr += 4) {
            u16x4 pk;
#pragma unroll
            for (int i = 0; i < 4; ++i)
                pk[i] = f2bf((half ? o1[rr + i] : o0[rr + i]) * rl);
            *(u16x4*)(op + half * 32 + (rr >> 2) * 8 + 4 * hi) = pk;
        }
    }
}

extern "C" void kernel_launch(void* const* d_in, const int* in_sizes, int n_in,
                              void* d_out, int out_size, void* d_ws, size_t ws_size,
                              hipStream_t stream) {
    const float* q  = (const float*)d_in[0];
    const float* k  = (const float*)d_in[1];
    const float* v  = (const float*)d_in[2];
    const float* Wq = (const float*)d_in[4];
    const float* bq = (const float*)d_in[5];
    const float* Wk = (const float*)d_in[6];
    const float* bk = (const float*)d_in[7];
    const float* Wv = (const float*)d_in[8];
    const float* bv = (const float*)d_in[9];
    const float* Wo = (const float*)d_in[10];
    const float* bo = (const float*)d_in[11];
    float* out = (float*)d_out;

    char* ws = (char*)d_ws;
    size_t off = 0;
    auto alloc = [&](size_t bytes) -> void* {
        void* p = ws + off;
        off += (bytes + 255) & ~(size_t)255;
        return p;
    };
    u16* Qp = (u16*)alloc((size_t)MS * D_MODEL * 2);
    u16* Kp = (u16*)alloc((size_t)MS * KVD * 2);
    u16* Vt = (u16*)alloc((size_t)MS * KVD * 2);   // [b][KVD][S_]
    u16* AO = (u16*)alloc((size_t)MS * D_MODEL * 2);

    gemm_qkv<<<384, 512, 0, stream>>>(q, k, v, Wq, Wk, Wv, bq, bk, bv, Qp, Kp, Vt);

    attn_fwd<<<16 * 64, 256, 0, stream>>>(Qp, Kp, Vt, AO);

    gemm_o<<<256, 512, 0, stream>>>(AO, Wo, bo, out);
}

// Round 6
// 209.500 us; speedup vs baseline: 1.1441x; 1.1441x over previous
//
#include <hip/hip_runtime.h>
#include <cstdint>

#define D_MODEL 2048
#define NKV 8
#define GQ 4
#define DK 64
#define B_ 2
#define S_ 2048
#define MS (B_*S_)     // 4096
#define KVD (NKV*DK)   // 512

typedef unsigned short u16;
typedef __attribute__((ext_vector_type(8))) short bf16x8;
typedef __attribute__((ext_vector_type(4))) short bf16x4;
typedef __attribute__((ext_vector_type(4))) float f32x4;
typedef __attribute__((ext_vector_type(16))) float f32x16;
typedef __attribute__((ext_vector_type(4))) unsigned short u16x4;

__device__ __forceinline__ u16 f2bf(float f) {
    union { float f; uint32_t u; } x; x.f = f;
    uint32_t u = x.u;
    uint32_t r = (u + 0x7FFFu + ((u >> 16) & 1u)) >> 16;
    return (u16)r;
}
__device__ __forceinline__ float bf2f(u16 h) {
    union { uint32_t u; float f; } x; x.u = ((uint32_t)h) << 16;
    return x.f;
}

__device__ __forceinline__ void gload_lds16(const void* g, void* lds) {
    __builtin_amdgcn_global_load_lds(
        (const __attribute__((address_space(1))) void*)g,
        (__attribute__((address_space(3))) void*)lds, 16, 0, 0);
}

__device__ __forceinline__ bf16x8 cvt8(float4 a, float4 b) {
    union { unsigned u[4]; bf16x8 v; } r;
    asm("v_cvt_pk_bf16_f32 %0, %1, %2" : "=v"(r.u[0]) : "v"(a.x), "v"(a.y));
    asm("v_cvt_pk_bf16_f32 %0, %1, %2" : "=v"(r.u[1]) : "v"(a.z), "v"(a.w));
    asm("v_cvt_pk_bf16_f32 %0, %1, %2" : "=v"(r.u[2]) : "v"(b.x), "v"(b.y));
    asm("v_cvt_pk_bf16_f32 %0, %1, %2" : "=v"(r.u[3]) : "v"(b.z), "v"(b.w));
    return r.v;
}

// =================== merged Q/K/V projection GEMM ===================
// 128x128 tile, BK=64, 256 thr (4 waves 2Mx2N, 64x64/wave), 64KB LDS -> 2 blocks/CU.
// fp32 A/B read to regs, cvt_pk to bf16, ds_write with 3-bit XOR swizzle.
// One barrier per K-step: WRITE(q^1) | MFMA(q) | LOAD(t+2) | lgkm0+barrier.
__global__ __launch_bounds__(256, 2)
void gemm_qkv(const float* __restrict__ Aq, const float* __restrict__ Ak,
              const float* __restrict__ Av,
              const float* __restrict__ Wq, const float* __restrict__ Wk,
              const float* __restrict__ Wv,
              const float* __restrict__ bq, const float* __restrict__ bk,
              const float* __restrict__ bv,
              u16* __restrict__ Qp, u16* __restrict__ Kp, u16* __restrict__ Vt) {
    __shared__ __align__(16) u16 SA[2][128 * 64];
    __shared__ __align__(16) u16 SB[2][128 * 64];
    const int tid = threadIdx.x;
    const int lane = tid & 63;
    const int fr = lane & 15, fq = lane >> 4;
    const int w = tid >> 6;
    const int wr = w >> 1, wc = w & 1;
    const int K = D_MODEL, NT = K / 64;   // 32

    const int bid = blockIdx.x;
    const int sw = (bid & 7) * 96 + (bid >> 3);      // bijective XCD swizzle (768)
    const float* A; const float* Bw; const float* bias;
    int seg, by, bx;
    if (sw < 512)      { seg = 0; A = Aq; Bw = Wq; bias = bq; by = sw >> 4;         bx = sw & 15; }
    else if (sw < 640) { seg = 1; A = Ak; Bw = Wk; bias = bk; by = (sw - 512) >> 2; bx = (sw - 512) & 3; }
    else               { seg = 2; A = Av; Bw = Wv; bias = bv; by = (sw - 640) >> 2; bx = (sw - 640) & 3; }
    const int m0 = by * 128, n0 = bx * 128;

    // reg staging: 4 float4-pairs each for A and B (per thread 32 fp32 each)
    const int sr = tid >> 3, sc = tid & 7;    // row-base 0..31, slot 0..7
    float4 ra[4][2], rb[4][2];
    auto LOADA = [&](int t) {
        const float* p0 = A + (size_t)(m0 + sr) * K + (t << 6) + sc * 8;
#pragma unroll
        for (int j = 0; j < 4; ++j) {
            const float* p = p0 + (size_t)(j * 32) * K;
            ra[j][0] = *(const float4*)p; ra[j][1] = *(const float4*)(p + 4);
        }
    };
    auto LOADB = [&](int t) {
        const float* p0 = Bw + (size_t)(n0 + sr) * K + (t << 6) + sc * 8;
#pragma unroll
        for (int j = 0; j < 4; ++j) {
            const float* p = p0 + (size_t)(j * 32) * K;
            rb[j][0] = *(const float4*)p; rb[j][1] = *(const float4*)(p + 4);
        }
    };
    auto WRITE = [&](int q) {
#pragma unroll
        for (int j = 0; j < 4; ++j) {
            int row = j * 32 + sr;
            *(bf16x8*)((char*)&SA[q][0] + row * 128 + ((sc ^ (row & 7)) * 16)) = cvt8(ra[j][0], ra[j][1]);
        }
#pragma unroll
        for (int j = 0; j < 4; ++j) {
            int row = j * 32 + sr;
            *(bf16x8*)((char*)&SB[q][0] + row * 128 + ((sc ^ (row & 7)) * 16)) = cvt8(rb[j][0], rb[j][1]);
        }
    };

    f32x4 acc[4][4] = {};
    const int arow = wr * 64, brow = wc * 64;

    LOADA(0); LOADB(0);
    WRITE(0);
    LOADA(1); LOADB(1);
    asm volatile("s_waitcnt lgkmcnt(0)" ::: "memory");
    __builtin_amdgcn_s_barrier();
    __builtin_amdgcn_sched_barrier(0);

    for (int t = 0; t < NT; ++t) {
        const int q = t & 1;
        if (t + 1 < NT) WRITE(q ^ 1);          // stage tile t+1 (regs from iter t-1)
        const char* sa = (const char*)&SA[q][0];
        const char* sb = (const char*)&SB[q][0];
#pragma unroll
        for (int kk = 0; kk < 2; ++kk) {
            const int cs = (((kk << 2) | fq) ^ (fr & 7)) * 16;
            bf16x8 af[4], bfr[4];
#pragma unroll
            for (int m = 0; m < 4; ++m)
                af[m] = *(const bf16x8*)(sa + (size_t)(arow + m * 16 + fr) * 128 + cs);
#pragma unroll
            for (int n = 0; n < 4; ++n)
                bfr[n] = *(const bf16x8*)(sb + (size_t)(brow + n * 16 + fr) * 128 + cs);
            __builtin_amdgcn_s_setprio(1);
#pragma unroll
            for (int m = 0; m < 4; ++m)
#pragma unroll
                for (int n = 0; n < 4; ++n)
                    acc[m][n] = __builtin_amdgcn_mfma_f32_16x16x32_bf16(af[m], bfr[n], acc[m][n], 0, 0, 0);
            __builtin_amdgcn_s_setprio(0);
        }
        if (t + 2 < NT) { LOADA(t + 2); LOADB(t + 2); }   // refill regs (2-iter lead)
        if (t + 1 < NT) {
            asm volatile("s_waitcnt lgkmcnt(0)" ::: "memory");
            __builtin_amdgcn_s_barrier();
            __builtin_amdgcn_sched_barrier(0);
        }
    }

    float bvv[4];
#pragma unroll
    for (int n = 0; n < 4; ++n) bvv[n] = bias[n0 + brow + n * 16 + fr];
#pragma unroll
    for (int m = 0; m < 4; ++m) {
        int grow0 = m0 + arow + m * 16 + fq * 4;
#pragma unroll
        for (int n = 0; n < 4; ++n) {
            int gcol = n0 + brow + n * 16 + fr;
#pragma unroll
            for (int r = 0; r < 4; ++r) {
                float v = acc[m][n][r] + bvv[n];
                int grow = grow0 + r;
                if (seg == 0)      Qp[(size_t)grow * D_MODEL + gcol] = f2bf(v);
                else if (seg == 1) Kp[(size_t)grow * KVD + gcol] = f2bf(v);
                else {
                    int b = grow >> 11, s = grow & (S_ - 1);
                    Vt[((size_t)b * KVD + gcol) * S_ + s] = f2bf(v);
                }
            }
        }
    }
}

// =================== O projection: A bf16 (gload_lds), B fp32 (reg-staged) ===================
__global__ __launch_bounds__(512, 2)
void gemm_o(const u16* __restrict__ A, const float* __restrict__ Bw,
            const float* __restrict__ bias, float* __restrict__ Cout) {
    __shared__ __align__(16) u16 SA[2][256 * 64];
    __shared__ __align__(16) u16 SB[2][128 * 64];
    const int tid = threadIdx.x;
    const int lane = tid & 63;
    const int fr = lane & 15, fq = lane >> 4;
    const int wid = tid >> 6;
    const int wr = wid >> 1, wc = wid & 1;
    const int K = D_MODEL, N = D_MODEL, NT = K / 64;

    const int bid = blockIdx.x;
    const int sw = (bid & 7) * 32 + (bid >> 3);
    const int by = sw >> 4, bx = sw & 15;
    const int m0 = by * 256, n0 = bx * 128;

    auto GLOADA = [&](int t, int q) {
        const int k0 = t << 6;
#pragma unroll
        for (int j = 0; j < 4; ++j) {
            int idx = tid + j * 512, row = idx >> 3, c = idx & 7;
            gload_lds16(A + (size_t)(m0 + row) * K + k0 + ((c ^ (row & 7)) * 8),
                        &SA[q][(j * 512 + (tid >> 6) * 64) * 8]);
        }
    };
    float4 rb[2][2];
    auto LOADB = [&](int t) {
        const int k0 = t << 6;
#pragma unroll
        for (int j = 0; j < 2; ++j) {
            int idx = tid + j * 512, row = idx >> 3, c = idx & 7;
            const float* p = Bw + (size_t)(n0 + row) * K + k0 + c * 8;
            rb[j][0] = *(const float4*)p;
            rb[j][1] = *(const float4*)(p + 4);
        }
    };
    auto WRITEB = [&](int q) {
#pragma unroll
        for (int j = 0; j < 2; ++j) {
            int idx = tid + j * 512, row = idx >> 3, c = idx & 7;
            *(bf16x8*)((char*)&SB[q][0] + row * 128 + ((c ^ (row & 7)) * 16)) = cvt8(rb[j][0], rb[j][1]);
        }
    };

    f32x4 acc[4][4] = {};
    const int arow = wr * 64, brow = wc * 64;

    GLOADA(0, 0);
    asm volatile("" ::: "memory");
    LOADB(0);
    WRITEB(0);
    GLOADA(1, 1);
    asm volatile("" ::: "memory");
    LOADB(1);
    asm volatile("s_waitcnt lgkmcnt(0)" ::: "memory");
    __builtin_amdgcn_s_barrier();

    for (int t = 0; t < NT; ++t) {
        const int q = t & 1;
        const char* sa = (const char*)&SA[q][0];
        const char* sb = (const char*)&SB[q][0];
#pragma unroll
        for (int kk = 0; kk < 2; ++kk) {
            const int cs = (((kk << 2) | fq) ^ (fr & 7)) * 16;
            bf16x8 af[4], bfr[4];
#pragma unroll
            for (int m = 0; m < 4; ++m)
                af[m] = *(const bf16x8*)(sa + (size_t)(arow + m * 16 + fr) * 128 + cs);
#pragma unroll
            for (int n = 0; n < 4; ++n)
                bfr[n] = *(const bf16x8*)(sb + (size_t)(brow + n * 16 + fr) * 128 + cs);
            __builtin_amdgcn_s_setprio(1);
#pragma unroll
            for (int m = 0; m < 4; ++m)
#pragma unroll
                for (int n = 0; n < 4; ++n)
                    acc[m][n] = __builtin_amdgcn_mfma_f32_16x16x32_bf16(af[m], bfr[n], acc[m][n], 0, 0, 0);
            __builtin_amdgcn_s_setprio(0);
        }
        asm volatile("s_barrier" ::: "memory");
        if (t + 1 < NT) {
            asm volatile("s_waitcnt vmcnt(4)" ::: "memory");
            WRITEB(q ^ 1);
            if (t + 2 < NT) {
                GLOADA(t + 2, q);
                asm volatile("" ::: "memory");
                LOADB(t + 2);
            }
            asm volatile("s_waitcnt lgkmcnt(0)" ::: "memory");
            __builtin_amdgcn_s_barrier();
        }
    }

    float bvv[4];
#pragma unroll
    for (int n = 0; n < 4; ++n) bvv[n] = bias[n0 + brow + n * 16 + fr];
#pragma unroll
    for (int m = 0; m < 4; ++m) {
        int grow0 = m0 + wr * 64 + m * 16 + fq * 4;
#pragma unroll
        for (int n = 0; n < 4; ++n) {
            int gcol = n0 + brow + n * 16 + fr;
#pragma unroll
            for (int r = 0; r < 4; ++r)
                Cout[(size_t)(grow0 + r) * N + gcol] = acc[m][n][r] + bvv[n];
        }
    }
}

// ---------------- Flash attention (causal, GQA), LDS-staged K/V ----------------
__global__ __launch_bounds__(256, 4)
void attn_fwd(const u16* __restrict__ Qp, const u16* __restrict__ Kp,
              const u16* __restrict__ Vt, u16* __restrict__ AO) {
    __shared__ __align__(16) u16 Klds[2][4096];
    __shared__ __align__(16) u16 Vlds[2][4096];
    const int bid = blockIdx.x;
    const int qblk = 15 - (bid >> 6);
    const int rest = bid & 63;
    const int b = rest >> 5;
    const int kv = (rest >> 2) & 7;
    const int g = rest & 3;
    const int tid = threadIdx.x, w = tid >> 6, l = tid & 63;
    const int q31 = l & 31, hi = l >> 5;
    const int h = kv * GQ + g;
    const int qw = qblk * 128 + w * 32;
    const int q0 = qw + q31;

    const u16* kbase = Kp + (size_t)(b * S_) * KVD + kv * DK;
    const u16* vbase = Vt + ((size_t)b * KVD + kv * DK) * S_;

    const float SCALE = 0.125f * 1.44269504f;
    bf16x8 qf[4];
    const u16* qp = Qp + ((size_t)(b * S_) + q0) * D_MODEL + h * DK;
#pragma unroll
    for (int ks = 0; ks < 4; ++ks) {
        bf16x8 t = *(const bf16x8*)(qp + ks * 16 + hi * 8);
#pragma unroll
        for (int j = 0; j < 8; ++j) t[j] = (short)f2bf(bf2f((u16)t[j]) * SCALE);
        qf[ks] = t;
    }

    const int nt = 2 * qblk + 2;
    const int bound = (qw + 31) >> 6;

    auto STAGE = [&](int t, int bufsel) {
#pragma unroll
        for (int r = 0; r < 2; ++r) {
            int idx = r * 256 + tid;
            int row = idx >> 3;
            int slotK = (idx & 7) ^ (row & 7);
            int jV = (idx & 7) ^ ((row >> 1) & 7);
            u16* kdst = &Klds[bufsel][(r * 256 + w * 64) * 8];
            u16* vdst = &Vlds[bufsel][(r * 256 + w * 64) * 8];
            gload_lds16(kbase + (size_t)(t * 64 + row) * KVD + slotK * 8, kdst);
            gload_lds16(vbase + (size_t)row * S_ + t * 64 + jV * 8, vdst);
        }
    };

    f32x16 o0 = {}, o1 = {};
    float m_run = -1e30f, l_run = 0.f;

    STAGE(0, 0);
    __syncthreads();
    int cur = 0;
    for (int t = 0; t < nt; ++t) {
        if (t + 1 < nt) STAGE(t + 1, cur ^ 1);
        if (t <= bound) {
            const u16* Kc = Klds[cur];
            const u16* Vc = Vlds[cur];
            const int base0 = t * 64, base1 = t * 64 + 32;
            const bool act1 = (base1 <= qw + 31);

            f32x16 s0 = {};
            {
                const int row = q31;
#pragma unroll
                for (int ks = 0; ks < 4; ++ks) {
                    bf16x8 kf = *(const bf16x8*)&Kc[row * 64 + ((((ks << 1) | hi)) ^ (row & 7)) * 8];
                    s0 = __builtin_amdgcn_mfma_f32_32x32x16_bf16(kf, qf[ks], s0, 0, 0, 0);
                }
            }
            f32x16 s1 = {};
            if (act1) {
                const int row = 32 + q31;
#pragma unroll
                for (int ks = 0; ks < 4; ++ks) {
                    bf16x8 kf = *(const bf16x8*)&Kc[row * 64 + ((((ks << 1) | hi)) ^ (row & 7)) * 8];
                    s1 = __builtin_amdgcn_mfma_f32_32x32x16_bf16(kf, qf[ks], s1, 0, 0, 0);
                }
            }
            if (base0 + 31 > qw) {
#pragma unroll
                for (int r = 0; r < 16; ++r) {
                    int koff = (r & 3) + 8 * (r >> 2) + 4 * hi;
                    s0[r] = (base0 + koff <= q0) ? s0[r] : -1e30f;
                }
            }
            if (act1 && (base1 + 31 > qw)) {
#pragma unroll
                for (int r = 0; r < 16; ++r) {
                    int koff = (r & 3) + 8 * (r >> 2) + 4 * hi;
                    s1[r] = (base1 + koff <= q0) ? s1[r] : -1e30f;
                }
            }
            float pm = s0[0];
#pragma unroll
            for (int r = 1; r < 16; ++r) pm = fmaxf(pm, s0[r]);
            if (act1) {
#pragma unroll
                for (int r = 0; r < 16; ++r) pm = fmaxf(pm, s1[r]);
            }
            pm = fmaxf(pm, __shfl_xor(pm, 32));
            if (__any(pm > m_run + 8.0f)) {
                float mn = fmaxf(m_run, pm);
                float sc = __builtin_amdgcn_exp2f(m_run - mn);
                m_run = mn; l_run *= sc;
#pragma unroll
                for (int r = 0; r < 16; ++r) { o0[r] *= sc; o1[r] *= sc; }
            }
            float psum = 0.f;
#pragma unroll
            for (int r = 0; r < 16; ++r) { float p = __builtin_amdgcn_exp2f(s0[r] - m_run); s0[r] = p; psum += p; }
            if (act1) {
#pragma unroll
                for (int r = 0; r < 16; ++r) { float p = __builtin_amdgcn_exp2f(s1[r] - m_run); s1[r] = p; psum += p; }
            }
            l_run += psum;
            unsigned W0[8], W1[8];
#pragma unroll
            for (int tt = 0; tt < 8; ++tt)
                asm("v_cvt_pk_bf16_f32 %0, %1, %2" : "=v"(W0[tt]) : "v"(s0[2 * tt]), "v"(s0[2 * tt + 1]));
            if (act1) {
#pragma unroll
                for (int tt = 0; tt < 8; ++tt)
                    asm("v_cvt_pk_bf16_f32 %0, %1, %2" : "=v"(W1[tt]) : "v"(s1[2 * tt]), "v"(s1[2 * tt + 1]));
            }
#pragma unroll
            for (int sl = 0; sl < 2; ++sl) {
                union { unsigned u[4]; bf16x8 v; } bw;
#pragma unroll
                for (int i = 0; i < 4; ++i) bw.u[i] = W0[sl * 4 + i];
#pragma unroll
                for (int half = 0; half < 2; ++half) {
                    const int row = half * 32 + q31;
                    union { bf16x4 h4[2]; bf16x8 v; } vf;
                    int sa = (sl * 4 + hi) ^ (row & 14);
                    int sb = (sl * 4 + 2 + hi) ^ (row & 14);
                    vf.h4[0] = *(const bf16x4*)&Vc[row * 64 + sa * 4];
                    vf.h4[1] = *(const bf16x4*)&Vc[row * 64 + sb * 4];
                    if (half == 0) o0 = __builtin_amdgcn_mfma_f32_32x32x16_bf16(vf.v, bw.v, o0, 0, 0, 0);
                    else           o1 = __builtin_amdgcn_mfma_f32_32x32x16_bf16(vf.v, bw.v, o1, 0, 0, 0);
                }
            }
            if (act1) {
#pragma unroll
                for (int sl = 2; sl < 4; ++sl) {
                    union { unsigned u[4]; bf16x8 v; } bw;
#pragma unroll
                    for (int i = 0; i < 4; ++i) bw.u[i] = W1[(sl - 2) * 4 + i];
#pragma unroll
                    for (int half = 0; half < 2; ++half) {
                        const int row = half * 32 + q31;
                        union { bf16x4 h4[2]; bf16x8 v; } vf;
                        int sa = (sl * 4 + hi) ^ (row & 14);
                        int sb = (sl * 4 + 2 + hi) ^ (row & 14);
                        vf.h4[0] = *(const bf16x4*)&Vc[row * 64 + sa * 4];
                        vf.h4[1] = *(const bf16x4*)&Vc[row * 64 + sb * 4];
                        if (half == 0) o0 = __builtin_amdgcn_mfma_f32_32x32x16_bf16(vf.v, bw.v, o0, 0, 0, 0);
                        else           o1 = __builtin_amdgcn_mfma_f32_32x32x16_bf16(vf.v, bw.v, o1, 0, 0, 0);
                    }
                }
            }
        }
        __syncthreads();
        cur ^= 1;
    }

    float lt = l_run + __shfl_xor(l_run, 32);
    float rl = 1.0f / lt;
    u16* op = AO + ((size_t)(b * S_) + q0) * D_MODEL + h * DK;
#pragma unroll
    for (int half = 0; half < 2; ++half) {
#pragma unroll
        for (int rr = 0; rr < 16; rr += 4) {
            u16x4 pk;
#pragma unroll
            for (int i = 0; i < 4; ++i)
                pk[i] = f2bf((half ? o1[rr + i] : o0[rr + i]) * rl);
            *(u16x4*)(op + half * 32 + (rr >> 2) * 8 + 4 * hi) = pk;
        }
    }
}

extern "C" void kernel_launch(void* const* d_in, const int* in_sizes, int n_in,
                              void* d_out, int out_size, void* d_ws, size_t ws_size,
                              hipStream_t stream) {
    const float* q  = (const float*)d_in[0];
    const float* k  = (const float*)d_in[1];
    const float* v  = (const float*)d_in[2];
    const float* Wq = (const float*)d_in[4];
    const float* bq = (const float*)d_in[5];
    const float* Wk = (const float*)d_in[6];
    const float* bk = (const float*)d_in[7];
    const float* Wv = (const float*)d_in[8];
    const float* bv = (const float*)d_in[9];
    const float* Wo = (const float*)d_in[10];
    const float* bo = (const float*)d_in[11];
    float* out = (float*)d_out;

    char* ws = (char*)d_ws;
    size_t off = 0;
    auto alloc = [&](size_t bytes) -> void* {
        void* p = ws + off;
        off += (bytes + 255) & ~(size_t)255;
        return p;
    };
    u16* Qp = (u16*)alloc((size_t)MS * D_MODEL * 2);
    u16* Kp = (u16*)alloc((size_t)MS * KVD * 2);
    u16* Vt = (u16*)alloc((size_t)MS * KVD * 2);   // [b][KVD][S_]
    u16* AO = (u16*)alloc((size_t)MS * D_MODEL * 2);

    gemm_qkv<<<768, 256, 0, stream>>>(q, k, v, Wq, Wk, Wv, bq, bk, bv, Qp, Kp, Vt);

    attn_fwd<<<16 * 64, 256, 0, stream>>>(Qp, Kp, Vt, AO);

    gemm_o<<<256, 512, 0, stream>>>(AO, Wo, bo, out);
}

// Round 7
// 197.732 us; speedup vs baseline: 1.2121x; 1.0595x over previous
//
#include <hip/hip_runtime.h>
#include <cstdint>

#define D_MODEL 2048
#define NKV 8
#define GQ 4
#define DK 64
#define B_ 2
#define S_ 2048
#define MS (B_*S_)     // 4096
#define KVD (NKV*DK)   // 512

typedef unsigned short u16;
typedef __attribute__((ext_vector_type(8))) short bf16x8;
typedef __attribute__((ext_vector_type(4))) short bf16x4;
typedef __attribute__((ext_vector_type(4))) float f32x4;
typedef __attribute__((ext_vector_type(16))) float f32x16;
typedef __attribute__((ext_vector_type(4))) unsigned short u16x4;

__device__ __forceinline__ u16 f2bf(float f) {
    union { float f; uint32_t u; } x; x.f = f;
    uint32_t u = x.u;
    uint32_t r = (u + 0x7FFFu + ((u >> 16) & 1u)) >> 16;
    return (u16)r;
}
__device__ __forceinline__ float bf2f(u16 h) {
    union { uint32_t u; float f; } x; x.u = ((uint32_t)h) << 16;
    return x.f;
}

__device__ __forceinline__ void gload_lds16(const void* g, void* lds) {
    __builtin_amdgcn_global_load_lds(
        (const __attribute__((address_space(1))) void*)g,
        (__attribute__((address_space(3))) void*)lds, 16, 0, 0);
}

__device__ __forceinline__ bf16x8 cvt8(float4 a, float4 b) {
    union { unsigned u[4]; bf16x8 v; } r;
    asm("v_cvt_pk_bf16_f32 %0, %1, %2" : "=v"(r.u[0]) : "v"(a.x), "v"(a.y));
    asm("v_cvt_pk_bf16_f32 %0, %1, %2" : "=v"(r.u[1]) : "v"(a.z), "v"(a.w));
    asm("v_cvt_pk_bf16_f32 %0, %1, %2" : "=v"(r.u[2]) : "v"(b.x), "v"(b.y));
    asm("v_cvt_pk_bf16_f32 %0, %1, %2" : "=v"(r.u[3]) : "v"(b.z), "v"(b.w));
    return r.v;
}

// =================== merged Q/K/V projection GEMM ===================
// 128x128 tile, BK=32, 256 thr (4 waves 2Mx2N), 32KB LDS -> 3 blocks/CU (768 all resident).
// fp32 A/B -> regs -> cvt_pk bf16 -> ds_write (pair-XOR swizzle).
// Per K-step: WRITE(q^1) | LOAD(t+2) | MFMA(q) | lgkm0 + barrier  (single barrier rotation).
__global__ __launch_bounds__(256, 3)
void gemm_qkv(const float* __restrict__ Aq, const float* __restrict__ Ak,
              const float* __restrict__ Av,
              const float* __restrict__ Wq, const float* __restrict__ Wk,
              const float* __restrict__ Wv,
              const float* __restrict__ bq, const float* __restrict__ bk,
              const float* __restrict__ bv,
              u16* __restrict__ Qp, u16* __restrict__ Kp, u16* __restrict__ Vt) {
    __shared__ __align__(16) u16 SA[2][128 * 32];
    __shared__ __align__(16) u16 SB[2][128 * 32];
    const int tid = threadIdx.x;
    const int lane = tid & 63;
    const int fr = lane & 15, fq = lane >> 4;
    const int w = tid >> 6;
    const int wr = w >> 1, wc = w & 1;
    const int K = D_MODEL, NT = K / 32;   // 64

    const int bid = blockIdx.x;
    const int sw = (bid & 7) * 96 + (bid >> 3);      // bijective XCD swizzle (768)
    const float* A; const float* Bw; const float* bias;
    int seg, by, bx;
    if (sw < 512)      { seg = 0; A = Aq; Bw = Wq; bias = bq; by = sw >> 4;         bx = sw & 15; }
    else if (sw < 640) { seg = 1; A = Ak; Bw = Wk; bias = bk; by = (sw - 512) >> 2; bx = (sw - 512) & 3; }
    else               { seg = 2; A = Av; Bw = Wv; bias = bv; by = (sw - 640) >> 2; bx = (sw - 640) & 3; }
    const int m0 = by * 128, n0 = bx * 128;

    // staging: chunk = 8 cols of one row; idx = tid + j*256; row = idx>>2 (sr, sr+64), slot = idx&3
    const int sr = tid >> 2, sc = tid & 3;
    float4 ra[2][2], rb[2][2];
    auto LOADA = [&](int t) {
        const float* p0 = A + (size_t)(m0 + sr) * K + (t << 5) + sc * 8;
#pragma unroll
        for (int j = 0; j < 2; ++j) {
            const float* p = p0 + (size_t)(j * 64) * K;
            ra[j][0] = *(const float4*)p; ra[j][1] = *(const float4*)(p + 4);
        }
    };
    auto LOADB = [&](int t) {
        const float* p0 = Bw + (size_t)(n0 + sr) * K + (t << 5) + sc * 8;
#pragma unroll
        for (int j = 0; j < 2; ++j) {
            const float* p = p0 + (size_t)(j * 64) * K;
            rb[j][0] = *(const float4*)p; rb[j][1] = *(const float4*)(p + 4);
        }
    };
    auto WRITE = [&](int q) {
#pragma unroll
        for (int j = 0; j < 2; ++j) {
            int row = j * 64 + sr;
            int s = (sc ^ ((row >> 1) & 3)) << 4;
            *(bf16x8*)((char*)&SA[q][0] + row * 64 + s) = cvt8(ra[j][0], ra[j][1]);
            *(bf16x8*)((char*)&SB[q][0] + row * 64 + s) = cvt8(rb[j][0], rb[j][1]);
        }
    };

    f32x4 acc[4][4] = {};
    const int arow = wr * 64, brow = wc * 64;

    LOADA(0); LOADB(0);
    WRITE(0);
    LOADA(1); LOADB(1);
    asm volatile("s_waitcnt lgkmcnt(0)" ::: "memory");
    __builtin_amdgcn_s_barrier();

    for (int t = 0; t < NT; ++t) {
        const int q = t & 1;
        if (t + 1 < NT) WRITE(q ^ 1);                      // stage tile t+1
        if (t + 2 < NT) { LOADA(t + 2); LOADB(t + 2); }    // issue loads EARLY (cover = MFMA phase)
        const char* sa = (const char*)&SA[q][0];
        const char* sb = (const char*)&SB[q][0];
        bf16x8 af[4], bfr[4];
#pragma unroll
        for (int m = 0; m < 4; ++m) {
            int row = arow + m * 16 + fr;
            af[m] = *(const bf16x8*)(sa + row * 64 + ((fq ^ ((row >> 1) & 3)) << 4));
        }
#pragma unroll
        for (int n = 0; n < 4; ++n) {
            int row = brow + n * 16 + fr;
            bfr[n] = *(const bf16x8*)(sb + row * 64 + ((fq ^ ((row >> 1) & 3)) << 4));
        }
        __builtin_amdgcn_s_setprio(1);
#pragma unroll
        for (int m = 0; m < 4; ++m)
#pragma unroll
            for (int n = 0; n < 4; ++n)
                acc[m][n] = __builtin_amdgcn_mfma_f32_16x16x32_bf16(af[m], bfr[n], acc[m][n], 0, 0, 0);
        __builtin_amdgcn_s_setprio(0);
        asm volatile("s_waitcnt lgkmcnt(0)" ::: "memory");
        __builtin_amdgcn_s_barrier();
    }

    float bvv[4];
#pragma unroll
    for (int n = 0; n < 4; ++n) bvv[n] = bias[n0 + brow + n * 16 + fr];
#pragma unroll
    for (int m = 0; m < 4; ++m) {
        int grow0 = m0 + arow + m * 16 + fq * 4;
#pragma unroll
        for (int n = 0; n < 4; ++n) {
            int gcol = n0 + brow + n * 16 + fr;
#pragma unroll
            for (int r = 0; r < 4; ++r) {
                float v = acc[m][n][r] + bvv[n];
                int grow = grow0 + r;
                if (seg == 0)      Qp[(size_t)grow * D_MODEL + gcol] = f2bf(v);
                else if (seg == 1) Kp[(size_t)grow * KVD + gcol] = f2bf(v);
                else {
                    int b = grow >> 11, s = grow & (S_ - 1);
                    Vt[((size_t)b * KVD + gcol) * S_ + s] = f2bf(v);
                }
            }
        }
    }
}

// =================== O projection: A bf16 reg-staged, B fp32 cvt-in-reg ===================
// Same 128x128/BK=32 template; grid 512 = exactly 2 blocks/CU.
__global__ __launch_bounds__(256, 3)
void gemm_o(const u16* __restrict__ A, const float* __restrict__ Bw,
            const float* __restrict__ bias, float* __restrict__ Cout) {
    __shared__ __align__(16) u16 SA[2][128 * 32];
    __shared__ __align__(16) u16 SB[2][128 * 32];
    const int tid = threadIdx.x;
    const int lane = tid & 63;
    const int fr = lane & 15, fq = lane >> 4;
    const int w = tid >> 6;
    const int wr = w >> 1, wc = w & 1;
    const int K = D_MODEL, N = D_MODEL, NT = K / 32;

    const int bid = blockIdx.x;
    const int sw = (bid & 7) * 64 + (bid >> 3);      // bijective XCD swizzle (512)
    const int by = sw >> 4, bx = sw & 15;
    const int m0 = by * 128, n0 = bx * 128;

    const int sr = tid >> 2, sc = tid & 3;
    bf16x8 rA[2];
    float4 rb[2][2];
    auto LOADA = [&](int t) {
        const u16* p0 = A + (size_t)(m0 + sr) * K + (t << 5) + sc * 8;
#pragma unroll
        for (int j = 0; j < 2; ++j)
            rA[j] = *(const bf16x8*)(p0 + (size_t)(j * 64) * K);
    };
    auto LOADB = [&](int t) {
        const float* p0 = Bw + (size_t)(n0 + sr) * K + (t << 5) + sc * 8;
#pragma unroll
        for (int j = 0; j < 2; ++j) {
            const float* p = p0 + (size_t)(j * 64) * K;
            rb[j][0] = *(const float4*)p; rb[j][1] = *(const float4*)(p + 4);
        }
    };
    auto WRITE = [&](int q) {
#pragma unroll
        for (int j = 0; j < 2; ++j) {
            int row = j * 64 + sr;
            int s = (sc ^ ((row >> 1) & 3)) << 4;
            *(bf16x8*)((char*)&SA[q][0] + row * 64 + s) = rA[j];
            *(bf16x8*)((char*)&SB[q][0] + row * 64 + s) = cvt8(rb[j][0], rb[j][1]);
        }
    };

    f32x4 acc[4][4] = {};
    const int arow = wr * 64, brow = wc * 64;

    LOADA(0); LOADB(0);
    WRITE(0);
    LOADA(1); LOADB(1);
    asm volatile("s_waitcnt lgkmcnt(0)" ::: "memory");
    __builtin_amdgcn_s_barrier();

    for (int t = 0; t < NT; ++t) {
        const int q = t & 1;
        if (t + 1 < NT) WRITE(q ^ 1);
        if (t + 2 < NT) { LOADA(t + 2); LOADB(t + 2); }
        const char* sa = (const char*)&SA[q][0];
        const char* sb = (const char*)&SB[q][0];
        bf16x8 af[4], bfr[4];
#pragma unroll
        for (int m = 0; m < 4; ++m) {
            int row = arow + m * 16 + fr;
            af[m] = *(const bf16x8*)(sa + row * 64 + ((fq ^ ((row >> 1) & 3)) << 4));
        }
#pragma unroll
        for (int n = 0; n < 4; ++n) {
            int row = brow + n * 16 + fr;
            bfr[n] = *(const bf16x8*)(sb + row * 64 + ((fq ^ ((row >> 1) & 3)) << 4));
        }
        __builtin_amdgcn_s_setprio(1);
#pragma unroll
        for (int m = 0; m < 4; ++m)
#pragma unroll
            for (int n = 0; n < 4; ++n)
                acc[m][n] = __builtin_amdgcn_mfma_f32_16x16x32_bf16(af[m], bfr[n], acc[m][n], 0, 0, 0);
        __builtin_amdgcn_s_setprio(0);
        asm volatile("s_waitcnt lgkmcnt(0)" ::: "memory");
        __builtin_amdgcn_s_barrier();
    }

    float bvv[4];
#pragma unroll
    for (int n = 0; n < 4; ++n) bvv[n] = bias[n0 + brow + n * 16 + fr];
#pragma unroll
    for (int m = 0; m < 4; ++m) {
        int grow0 = m0 + arow + m * 16 + fq * 4;
#pragma unroll
        for (int n = 0; n < 4; ++n) {
            int gcol = n0 + brow + n * 16 + fr;
#pragma unroll
            for (int r = 0; r < 4; ++r)
                Cout[(size_t)(grow0 + r) * N + gcol] = acc[m][n][r] + bvv[n];
        }
    }
}

// ---------------- Flash attention (causal, GQA), LDS-staged K/V ----------------
__global__ __launch_bounds__(256, 4)
void attn_fwd(const u16* __restrict__ Qp, const u16* __restrict__ Kp,
              const u16* __restrict__ Vt, u16* __restrict__ AO) {
    __shared__ __align__(16) u16 Klds[2][4096];
    __shared__ __align__(16) u16 Vlds[2][4096];
    const int bid = blockIdx.x;
    const int qblk = 15 - (bid >> 6);
    const int rest = bid & 63;
    const int b = rest >> 5;
    const int kv = (rest >> 2) & 7;
    const int g = rest & 3;
    const int tid = threadIdx.x, w = tid >> 6, l = tid & 63;
    const int q31 = l & 31, hi = l >> 5;
    const int h = kv * GQ + g;
    const int qw = qblk * 128 + w * 32;
    const int q0 = qw + q31;

    const u16* kbase = Kp + (size_t)(b * S_) * KVD + kv * DK;
    const u16* vbase = Vt + ((size_t)b * KVD + kv * DK) * S_;

    const float SCALE = 0.125f * 1.44269504f;
    bf16x8 qf[4];
    const u16* qp = Qp + ((size_t)(b * S_) + q0) * D_MODEL + h * DK;
#pragma unroll
    for (int ks = 0; ks < 4; ++ks) {
        bf16x8 t = *(const bf16x8*)(qp + ks * 16 + hi * 8);
#pragma unroll
        for (int j = 0; j < 8; ++j) t[j] = (short)f2bf(bf2f((u16)t[j]) * SCALE);
        qf[ks] = t;
    }

    const int nt = 2 * qblk + 2;
    const int bound = (qw + 31) >> 6;

    auto STAGE = [&](int t, int bufsel) {
#pragma unroll
        for (int r = 0; r < 2; ++r) {
            int idx = r * 256 + tid;
            int row = idx >> 3;
            int slotK = (idx & 7) ^ (row & 7);
            int jV = (idx & 7) ^ ((row >> 1) & 7);
            u16* kdst = &Klds[bufsel][(r * 256 + w * 64) * 8];
            u16* vdst = &Vlds[bufsel][(r * 256 + w * 64) * 8];
            gload_lds16(kbase + (size_t)(t * 64 + row) * KVD + slotK * 8, kdst);
            gload_lds16(vbase + (size_t)row * S_ + t * 64 + jV * 8, vdst);
        }
    };

    f32x16 o0 = {}, o1 = {};
    float m_run = -1e30f, l_run = 0.f;

    STAGE(0, 0);
    __syncthreads();
    int cur = 0;
    for (int t = 0; t < nt; ++t) {
        if (t + 1 < nt) STAGE(t + 1, cur ^ 1);
        if (t <= bound) {
            const u16* Kc = Klds[cur];
            const u16* Vc = Vlds[cur];
            const int base0 = t * 64, base1 = t * 64 + 32;
            const bool act1 = (base1 <= qw + 31);

            f32x16 s0 = {};
            {
                const int row = q31;
#pragma unroll
                for (int ks = 0; ks < 4; ++ks) {
                    bf16x8 kf = *(const bf16x8*)&Kc[row * 64 + ((((ks << 1) | hi)) ^ (row & 7)) * 8];
                    s0 = __builtin_amdgcn_mfma_f32_32x32x16_bf16(kf, qf[ks], s0, 0, 0, 0);
                }
            }
            f32x16 s1 = {};
            if (act1) {
                const int row = 32 + q31;
#pragma unroll
                for (int ks = 0; ks < 4; ++ks) {
                    bf16x8 kf = *(const bf16x8*)&Kc[row * 64 + ((((ks << 1) | hi)) ^ (row & 7)) * 8];
                    s1 = __builtin_amdgcn_mfma_f32_32x32x16_bf16(kf, qf[ks], s1, 0, 0, 0);
                }
            }
            if (base0 + 31 > qw) {
#pragma unroll
                for (int r = 0; r < 16; ++r) {
                    int koff = (r & 3) + 8 * (r >> 2) + 4 * hi;
                    s0[r] = (base0 + koff <= q0) ? s0[r] : -1e30f;
                }
            }
            if (act1 && (base1 + 31 > qw)) {
#pragma unroll
                for (int r = 0; r < 16; ++r) {
                    int koff = (r & 3) + 8 * (r >> 2) + 4 * hi;
                    s1[r] = (base1 + koff <= q0) ? s1[r] : -1e30f;
                }
            }
            float pm = s0[0];
#pragma unroll
            for (int r = 1; r < 16; ++r) pm = fmaxf(pm, s0[r]);
            if (act1) {
#pragma unroll
                for (int r = 0; r < 16; ++r) pm = fmaxf(pm, s1[r]);
            }
            pm = fmaxf(pm, __shfl_xor(pm, 32));
            if (__any(pm > m_run + 8.0f)) {
                float mn = fmaxf(m_run, pm);
                float sc = __builtin_amdgcn_exp2f(m_run - mn);
                m_run = mn; l_run *= sc;
#pragma unroll
                for (int r = 0; r < 16; ++r) { o0[r] *= sc; o1[r] *= sc; }
            }
            float psum = 0.f;
#pragma unroll
            for (int r = 0; r < 16; ++r) { float p = __builtin_amdgcn_exp2f(s0[r] - m_run); s0[r] = p; psum += p; }
            if (act1) {
#pragma unroll
                for (int r = 0; r < 16; ++r) { float p = __builtin_amdgcn_exp2f(s1[r] - m_run); s1[r] = p; psum += p; }
            }
            l_run += psum;
            unsigned W0[8], W1[8];
#pragma unroll
            for (int tt = 0; tt < 8; ++tt)
                asm("v_cvt_pk_bf16_f32 %0, %1, %2" : "=v"(W0[tt]) : "v"(s0[2 * tt]), "v"(s0[2 * tt + 1]));
            if (act1) {
#pragma unroll
                for (int tt = 0; tt < 8; ++tt)
                    asm("v_cvt_pk_bf16_f32 %0, %1, %2" : "=v"(W1[tt]) : "v"(s1[2 * tt]), "v"(s1[2 * tt + 1]));
            }
#pragma unroll
            for (int sl = 0; sl < 2; ++sl) {
                union { unsigned u[4]; bf16x8 v; } bw;
#pragma unroll
                for (int i = 0; i < 4; ++i) bw.u[i] = W0[sl * 4 + i];
#pragma unroll
                for (int half = 0; half < 2; ++half) {
                    const int row = half * 32 + q31;
                    union { bf16x4 h4[2]; bf16x8 v; } vf;
                    int sa = (sl * 4 + hi) ^ (row & 14);
                    int sb = (sl * 4 + 2 + hi) ^ (row & 14);
                    vf.h4[0] = *(const bf16x4*)&Vc[row * 64 + sa * 4];
                    vf.h4[1] = *(const bf16x4*)&Vc[row * 64 + sb * 4];
                    if (half == 0) o0 = __builtin_amdgcn_mfma_f32_32x32x16_bf16(vf.v, bw.v, o0, 0, 0, 0);
                    else           o1 = __builtin_amdgcn_mfma_f32_32x32x16_bf16(vf.v, bw.v, o1, 0, 0, 0);
                }
            }
            if (act1) {
#pragma unroll
                for (int sl = 2; sl < 4; ++sl) {
                    union { unsigned u[4]; bf16x8 v; } bw;
#pragma unroll
                    for (int i = 0; i < 4; ++i) bw.u[i] = W1[(sl - 2) * 4 + i];
#pragma unroll
                    for (int half = 0; half < 2; ++half) {
                        const int row = half * 32 + q31;
                        union { bf16x4 h4[2]; bf16x8 v; } vf;
                        int sa = (sl * 4 + hi) ^ (row & 14);
                        int sb = (sl * 4 + 2 + hi) ^ (row & 14);
                        vf.h4[0] = *(const bf16x4*)&Vc[row * 64 + sa * 4];
                        vf.h4[1] = *(const bf16x4*)&Vc[row * 64 + sb * 4];
                        if (half == 0) o0 = __builtin_amdgcn_mfma_f32_32x32x16_bf16(vf.v, bw.v, o0, 0, 0, 0);
                        else           o1 = __builtin_amdgcn_mfma_f32_32x32x16_bf16(vf.v, bw.v, o1, 0, 0, 0);
                    }
                }
            }
        }
        __syncthreads();
        cur ^= 1;
    }

    float lt = l_run + __shfl_xor(l_run, 32);
    float rl = 1.0f / lt;
    u16* op = AO + ((size_t)(b * S_) + q0) * D_MODEL + h * DK;
#pragma unroll
    for (int half = 0; half < 2; ++half) {
#pragma unroll
        for (int rr = 0; rr < 16; rr += 4) {
            u16x4 pk;
#pragma unroll
            for (int i = 0; i < 4; ++i)
                pk[i] = f2bf((half ? o1[rr + i] : o0[rr + i]) * rl);
            *(u16x4*)(op + half * 32 + (rr >> 2) * 8 + 4 * hi) = pk;
        }
    }
}

extern "C" void kernel_launch(void* const* d_in, const int* in_sizes, int n_in,
                              void* d_out, int out_size, void* d_ws, size_t ws_size,
                              hipStream_t stream) {
    const float* q  = (const float*)d_in[0];
    const float* k  = (const float*)d_in[1];
    const float* v  = (const float*)d_in[2];
    const float* Wq = (const float*)d_in[4];
    const float* bq = (const float*)d_in[5];
    const float* Wk = (const float*)d_in[6];
    const float* bk = (const float*)d_in[7];
    const float* Wv = (const float*)d_in[8];
    const float* bv = (const float*)d_in[9];
    const float* Wo = (const float*)d_in[10];
    const float* bo = (const float*)d_in[11];
    float* out = (float*)d_out;

    char* ws = (char*)d_ws;
    size_t off = 0;
    auto alloc = [&](size_t bytes) -> void* {
        void* p = ws + off;
        off += (bytes + 255) & ~(size_t)255;
        return p;
    };
    u16* Qp = (u16*)alloc((size_t)MS * D_MODEL * 2);
    u16* Kp = (u16*)alloc((size_t)MS * KVD * 2);
    u16* Vt = (u16*)alloc((size_t)MS * KVD * 2);   // [b][KVD][S_]
    u16* AO = (u16*)alloc((size_t)MS * D_MODEL * 2);

    gemm_qkv<<<768, 256, 0, stream>>>(q, k, v, Wq, Wk, Wv, bq, bk, bv, Qp, Kp, Vt);

    attn_fwd<<<16 * 64, 256, 0, stream>>>(Qp, Kp, Vt, AO);

    gemm_o<<<512, 256, 0, stream>>>(AO, Wo, bo, out);
}